// Round 2
// baseline (1276.918 us; speedup 1.0000x reference)
//
#include <hip/hip_runtime.h>
#include <hip/hip_bf16.h>

// ---------------------------------------------------------------------------
// TiLISTA: M=512, N=2048, B=8192, T=5
//   x0 = mu0 * y @ A                      (shrink at t=0 is identity: idx=0)
//   for t=1..5:
//     r = x @ A^T - y        [B,512]   (fp32 in ws)
//     z = x - mu_t * (r @ A) [B,2048]
//     x = shrink(z, beta_t, k_t)   k_t = int(min(0.012 t, 0.12)*2048)
// GEMMs: split-bf16 (hi+lo) MFMA, 3 terms hi*hi + hi*lo + lo*hi, fp32 acc
// -> ~2^-17 relative input error, near-fp32 results.
// shrink = exact k-th-largest |z| via binary search on float bits, 1 wave/row.
// ---------------------------------------------------------------------------

typedef __bf16 bf16x8 __attribute__((ext_vector_type(8)));
typedef float  f32x4  __attribute__((ext_vector_type(4)));
typedef short  short4v __attribute__((ext_vector_type(4)));
typedef short  short8v __attribute__((ext_vector_type(8)));

__device__ __forceinline__ short f2b(float f) {
    // RNE float -> bf16 bits
    unsigned u = __float_as_uint(f);
    unsigned r = (u + 0x7FFFu + ((u >> 16) & 1u)) >> 16;
    return (short)(r & 0xFFFFu);
}
__device__ __forceinline__ float b2f(short h) {
    return __uint_as_float(((unsigned)(unsigned short)h) << 16);
}

// out[m][n] = epilogue( sum_k Aop[m][k] * Bop[k][n] )
// Aop: row-major fp32 [M][K], split to bf16 hi/lo during LDS staging.
// B operand: precast bf16 hi/lo planes in B^T layout, row-major [n][k].
// EPI 0: outF = s*acc          (h step)
// EPI 1: outF = acc - Y        (r step; Y = y, fp32 out)
// EPI 2: outF = Y - s*acc      (k step; Y = x, aliases outF, same-elem in place)
template<int NJ, int EPI>
__global__ __launch_bounds__(256) void gemm_kernel(
    const float* __restrict__ Af, int lda,
    const short* __restrict__ Bhi, const short* __restrict__ Blo, int ldb,
    const float* Yaux, float* outF,
    const float* __restrict__ scalePtr, int scaleIdx, int K, int ldOut)
{
    constexpr int BN = 32 * NJ;   // 128 (NJ=4) or 64 (NJ=2)
    constexpr int SK = 40;        // 32 + 8 pad; row = 80B = 5x16B (aligned, bank-spread)
    __shared__ short AsH[128 * SK];
    __shared__ short AsL[128 * SK];
    __shared__ short BsH[BN * SK];
    __shared__ short BsL[BN * SK];

    const int tid  = threadIdx.x;
    const int wid  = tid >> 6;
    const int lane = tid & 63;
    const int quad = lane >> 4;
    const int l16  = lane & 15;
    const int waveM = (wid >> 1) * 64;
    const int waveN = (wid & 1) * (16 * NJ);
    const int mBase = blockIdx.y * 128;
    const int nBase = blockIdx.x * BN;

    f32x4 acc[4][NJ] = {};

    for (int k0 = 0; k0 < K; k0 += 32) {
        // ---- stage A tile: 128 rows x 32 k, fp32 -> bf16 hi/lo split ----
        #pragma unroll
        for (int it = 0; it < 4; ++it) {
            int f4  = tid + it * 256;       // 0..1023 float4 chunks
            int row = f4 >> 3;
            int kq  = f4 & 7;
            const float4 v = *(const float4*)(Af + (size_t)(mBase + row) * lda + k0 + kq * 4);
            short4v h, l;
            h.x = f2b(v.x); l.x = f2b(v.x - b2f(h.x));
            h.y = f2b(v.y); l.y = f2b(v.y - b2f(h.y));
            h.z = f2b(v.z); l.z = f2b(v.z - b2f(h.z));
            h.w = f2b(v.w); l.w = f2b(v.w - b2f(h.w));
            *(short4v*)(&AsH[row * SK + kq * 4]) = h;
            *(short4v*)(&AsL[row * SK + kq * 4]) = l;
        }
        // ---- stage B tile: BN rows x 32 k (B^T layout, bf16 hi/lo planes) ----
        #pragma unroll
        for (int it = 0; it < BN / 64; ++it) {
            int f8  = tid + it * 256;
            int row = f8 >> 2;
            int ko  = (f8 & 3) * 8;
            size_t g = (size_t)(nBase + row) * ldb + k0 + ko;
            *(short8v*)(&BsH[row * SK + ko]) = *(const short8v*)(Bhi + g);
            *(short8v*)(&BsL[row * SK + ko]) = *(const short8v*)(Blo + g);
        }
        __syncthreads();

        bf16x8 ah[4], al[4], bh[NJ], bl[NJ];
        #pragma unroll
        for (int i = 0; i < 4; ++i) {
            int off = (waveM + i * 16 + l16) * SK + quad * 8;
            ah[i] = *(const bf16x8*)(&AsH[off]);
            al[i] = *(const bf16x8*)(&AsL[off]);
        }
        #pragma unroll
        for (int j = 0; j < NJ; ++j) {
            int off = (waveN + j * 16 + l16) * SK + quad * 8;
            bh[j] = *(const bf16x8*)(&BsH[off]);
            bl[j] = *(const bf16x8*)(&BsL[off]);
        }
        #pragma unroll
        for (int i = 0; i < 4; ++i)
            #pragma unroll
            for (int j = 0; j < NJ; ++j) {
                acc[i][j] = __builtin_amdgcn_mfma_f32_16x16x32_bf16(ah[i], bh[j], acc[i][j], 0, 0, 0);
                acc[i][j] = __builtin_amdgcn_mfma_f32_16x16x32_bf16(ah[i], bl[j], acc[i][j], 0, 0, 0);
                acc[i][j] = __builtin_amdgcn_mfma_f32_16x16x32_bf16(al[i], bh[j], acc[i][j], 0, 0, 0);
            }

        __syncthreads();
    }

    // ---- epilogue ----
    const float s = scalePtr[scaleIdx];
    #pragma unroll
    for (int i = 0; i < 4; ++i) {
        #pragma unroll
        for (int j = 0; j < NJ; ++j) {
            const int gr0 = mBase + waveM + i * 16 + quad * 4;
            const int gc  = nBase + waveN + j * 16 + l16;
            #pragma unroll
            for (int r = 0; r < 4; ++r) {
                size_t idx = (size_t)(gr0 + r) * ldOut + gc;
                if constexpr (EPI == 0)      outF[idx] = s * acc[i][j][r];
                else if constexpr (EPI == 1) outF[idx] = acc[i][j][r] - Yaux[idx];
                else                         outF[idx] = Yaux[idx] - s * acc[i][j][r];
            }
        }
    }
}

// cast A and W(=A^T) to bf16 hi/lo planes once per launch
__global__ void precast_kernel(const float* __restrict__ A,
                               short* __restrict__ Ahi, short* __restrict__ Alo,
                               const float* __restrict__ W,
                               short* __restrict__ WThi, short* __restrict__ WTlo, int n)
{
    int idx = blockIdx.x * 256 + threadIdx.x;
    int stride = gridDim.x * 256;
    for (int i = idx; i < n; i += stride) {
        float a = A[i];
        short h = f2b(a);
        Ahi[i] = h; Alo[i] = f2b(a - b2f(h));
        float w = W[i];
        short wh = f2b(w);
        WThi[i] = wh; WTlo[i] = f2b(w - b2f(wh));
    }
}

// one wave per row of x[.,2048]: exact kSel-th largest |x| (binary search on
// uint-ordered non-negative float bits), then hard-keep / soft-shrink in place.
__global__ __launch_bounds__(256) void shrink_kernel(
    float* __restrict__ x, const float* __restrict__ betaPtr, int tIdx, int kSel)
{
    const int tid  = threadIdx.x;
    const int wid  = tid >> 6;
    const int lane = tid & 63;
    const long long row = (long long)blockIdx.x * 4 + wid;
    const float beta = betaPtr[tIdx];
    float* xr = x + row * 2048;

    float v[32];
    #pragma unroll
    for (int c = 0; c < 8; ++c) {
        float4 f = ((const float4*)xr)[c * 64 + lane];
        v[c * 4 + 0] = f.x; v[c * 4 + 1] = f.y; v[c * 4 + 2] = f.z; v[c * 4 + 3] = f.w;
    }
    unsigned a[32];
    #pragma unroll
    for (int i = 0; i < 32; ++i) a[i] = __float_as_uint(fabsf(v[i]));

    // invariant: count(>= lo) >= k, count(>= hi) < k ; result lo = k-th largest bits
    unsigned lo = 0u, hi = 0x7F800000u;
    for (int it = 0; it < 31; ++it) {
        unsigned mid = (lo + hi) >> 1;
        int cnt = 0;
        #pragma unroll
        for (int i = 0; i < 32; ++i) cnt += (a[i] >= mid) ? 1 : 0;
        #pragma unroll
        for (int off = 32; off >= 1; off >>= 1) cnt += __shfl_xor(cnt, off, 64);
        if (cnt >= kSel) lo = mid; else hi = mid;
    }
    const unsigned thr = lo;

    #pragma unroll
    for (int i = 0; i < 32; ++i) {
        if (a[i] < thr) {   // |v| < thr  -> soft-shrink, else keep
            float av   = __uint_as_float(a[i]);
            float soft = fmaxf(av - beta, 0.f);
            v[i] = copysignf(soft, v[i]);
        }
    }
    #pragma unroll
    for (int c = 0; c < 8; ++c) {
        float4 f;
        f.x = v[c * 4 + 0]; f.y = v[c * 4 + 1]; f.z = v[c * 4 + 2]; f.w = v[c * 4 + 3];
        ((float4*)xr)[c * 64 + lane] = f;
    }
}

extern "C" void kernel_launch(void* const* d_in, const int* in_sizes, int n_in,
                              void* d_out, int out_size, void* d_ws, size_t ws_size,
                              hipStream_t stream)
{
    const float* y    = (const float*)d_in[0];   // [8192,512]
    const float* A    = (const float*)d_in[1];   // [512,2048]
    const float* W    = (const float*)d_in[2];   // [2048,512] == A^T exactly
    const float* beta = (const float*)d_in[3];   // [6]
    const float* mu   = (const float*)d_in[4];   // [6]
    float* out = (float*)d_out;                  // x lives here throughout

    // workspace layout (~25 MB)
    short* Ahi  = (short*)d_ws;            // [512][2048]  bf16 hi(A)
    short* Alo  = Ahi  + 512 * 2048;       // [512][2048]  bf16 lo(A)
    short* AThi = Alo  + 512 * 2048;       // [2048][512]  bf16 hi(A^T)
    short* ATlo = AThi + 2048 * 512;       // [2048][512]  bf16 lo(A^T)
    float* r    = (float*)(ATlo + 2048 * 512);  // [8192][512] fp32 residual

    precast_kernel<<<1024, 256, 0, stream>>>(A, Ahi, Alo, W, AThi, ATlo, 512 * 2048);

    // x = mu0 * y @ A   (B^T layout = A^T planes [2048][512])
    gemm_kernel<4, 0><<<dim3(16, 64), 256, 0, stream>>>(
        y, 512, AThi, ATlo, 512, nullptr, out, mu, 0, 512, 2048);

    for (int t = 1; t <= 5; ++t) {
        double p = 0.012 * t; if (p > 0.12) p = 0.12;
        int kSel = (int)(p * 2048.0);   // 24,49,73,98,122

        // r = x @ A^T - y   (B^T layout = A planes [512][2048])
        gemm_kernel<2, 1><<<dim3(8, 64), 256, 0, stream>>>(
            out, 2048, Ahi, Alo, 2048, y, r, mu, t, 2048, 512);

        // z = x - mu_t * (r @ A)   in place over x
        gemm_kernel<4, 2><<<dim3(16, 64), 256, 0, stream>>>(
            r, 512, AThi, ATlo, 512, out, out, mu, t, 512, 2048);

        // x = shrink(z)
        shrink_kernel<<<2048, 256, 0, stream>>>(out, beta, t, kSel);
    }
}

// Round 3
// 1150.778 us; speedup vs baseline: 1.1096x; 1.1096x over previous
//
#include <hip/hip_runtime.h>
#include <hip/hip_bf16.h>

// ---------------------------------------------------------------------------
// TiLISTA: M=512, N=2048, B=8192, T=5
//   x0 = mu0 * y @ A
//   for t=1..5:
//     r = x @ A^T - y        [B,512]   (bf16 hi/lo planes in ws)
//     z = x - mu_t * (r @ A) [B,2048]  (fp32 in d_out)
//     x = shrink(z, beta_t, k_t)       (bf16 hi/lo planes in ws)
// All GEMM operands are pre-split bf16 hi/lo planes -> staging is a pure copy
// via global_load_lds (width 16). 3-term split MFMA (hi*hi+hi*lo+lo*hi) gives
// ~2^-17 effective input precision. shrink = exact k-th |z| binary search.
// ---------------------------------------------------------------------------

typedef __bf16 bf16x8 __attribute__((ext_vector_type(8)));
typedef float  f32x4  __attribute__((ext_vector_type(4)));
typedef short  short4v __attribute__((ext_vector_type(4)));

__device__ __forceinline__ short f2b(float f) {
    unsigned u = __float_as_uint(f);
    unsigned r = (u + 0x7FFFu + ((u >> 16) & 1u)) >> 16;
    return (short)(r & 0xFFFFu);
}
__device__ __forceinline__ float b2f(short h) {
    return __uint_as_float(((unsigned)(unsigned short)h) << 16);
}

__device__ __forceinline__ void gl_lds16(const short* g, short* lds) {
    __builtin_amdgcn_global_load_lds(
        (const __attribute__((address_space(1))) void*)g,
        (__attribute__((address_space(3))) void*)lds, 16, 0, 0);
}

// out[m][n] = epilogue( sum_k Aop[m][k] * Bop[k][n] )
// Aop: bf16 hi/lo planes [M][K] (or fp32 Af split on stage if AF32).
// Bop: bf16 hi/lo planes in B^T layout [n][k].
// EPI 0: split(s*acc) -> Oh/Ol planes            (h step)
// EPI 1: split(acc - Y) -> Oh/Ol planes          (r step; Y = y)
// EPI 2: outF = (Xh+Xl) - s*acc  (fp32)          (z step; X = x planes)
template<int NJ, int EPI, bool AF32>
__global__ __launch_bounds__(256) void gemm_kernel(
    const float* __restrict__ Af,
    const short* __restrict__ Ah_p, const short* __restrict__ Al_p, int lda,
    const short* __restrict__ Bh_p, const short* __restrict__ Bl_p, int ldb,
    const float* __restrict__ Yaux,
    const short* __restrict__ Xh, const short* __restrict__ Xl,
    float* outF, short* Oh, short* Ol,
    const float* __restrict__ scalePtr, int scaleIdx, int K, int ldOut)
{
    constexpr int BN = 32 * NJ;   // 128 (NJ=4) or 64 (NJ=2)
    // packed SK=32 (64B rows) — required by global_load_lds lane-contiguity
    __shared__ short AsH[128 * 32];
    __shared__ short AsL[128 * 32];
    __shared__ short BsH[BN * 32];
    __shared__ short BsL[BN * 32];

    const int tid  = threadIdx.x;
    const int wid  = tid >> 6;
    const int lane = tid & 63;
    const int quad = lane >> 4;
    const int l16  = lane & 15;
    const int waveM = (wid >> 1) * 64;
    const int waveN = (wid & 1) * (16 * NJ);
    const int mBase = blockIdx.y * 128;
    const int nBase = blockIdx.x * BN;

    f32x4 acc[4][NJ] = {};

    for (int k0 = 0; k0 < K; k0 += 32) {
        // ---- stage A tile: 128 rows x 32 k ----
        if constexpr (AF32) {
            #pragma unroll
            for (int it = 0; it < 4; ++it) {
                int f4  = tid + it * 256;
                int row = f4 >> 3;
                int kq  = f4 & 7;
                const float4 v = *(const float4*)(Af + (size_t)(mBase + row) * lda + k0 + kq * 4);
                short4v h, l;
                h.x = f2b(v.x); l.x = f2b(v.x - b2f(h.x));
                h.y = f2b(v.y); l.y = f2b(v.y - b2f(h.y));
                h.z = f2b(v.z); l.z = f2b(v.z - b2f(h.z));
                h.w = f2b(v.w); l.w = f2b(v.w - b2f(h.w));
                *(short4v*)(&AsH[row * 32 + kq * 4]) = h;
                *(short4v*)(&AsL[row * 32 + kq * 4]) = l;
            }
        } else {
            #pragma unroll
            for (int rr = 0; rr < 2; ++rr) {
                int c   = rr * 256 + tid;       // 16B chunk id, 0..511
                int row = c >> 2;
                int ko  = (c & 3) * 8;
                size_t g = (size_t)(mBase + row) * lda + k0 + ko;
                short* dh = &AsH[(rr * 256 + wid * 64) * 8];  // wave-uniform base
                short* dl = &AsL[(rr * 256 + wid * 64) * 8];
                gl_lds16(Ah_p + g, dh);
                gl_lds16(Al_p + g, dl);
            }
        }
        // ---- stage B tile: BN rows x 32 k ----
        #pragma unroll
        for (int rr = 0; rr < BN / 64; ++rr) {
            int c   = rr * 256 + tid;
            int row = c >> 2;
            int ko  = (c & 3) * 8;
            size_t g = (size_t)(nBase + row) * ldb + k0 + ko;
            gl_lds16(Bh_p + g, &BsH[(rr * 256 + wid * 64) * 8]);
            gl_lds16(Bl_p + g, &BsL[(rr * 256 + wid * 64) * 8]);
        }
        __syncthreads();   // drains vmcnt (global_load_lds) before LDS reads

        bf16x8 ah[4], al[4], bh[NJ], bl[NJ];
        #pragma unroll
        for (int i = 0; i < 4; ++i) {
            int off = (waveM + i * 16 + l16) * 32 + quad * 8;
            ah[i] = *(const bf16x8*)(&AsH[off]);
            al[i] = *(const bf16x8*)(&AsL[off]);
        }
        #pragma unroll
        for (int j = 0; j < NJ; ++j) {
            int off = (waveN + j * 16 + l16) * 32 + quad * 8;
            bh[j] = *(const bf16x8*)(&BsH[off]);
            bl[j] = *(const bf16x8*)(&BsL[off]);
        }
        #pragma unroll
        for (int i = 0; i < 4; ++i)
            #pragma unroll
            for (int j = 0; j < NJ; ++j) {
                acc[i][j] = __builtin_amdgcn_mfma_f32_16x16x32_bf16(ah[i], bh[j], acc[i][j], 0, 0, 0);
                acc[i][j] = __builtin_amdgcn_mfma_f32_16x16x32_bf16(ah[i], bl[j], acc[i][j], 0, 0, 0);
                acc[i][j] = __builtin_amdgcn_mfma_f32_16x16x32_bf16(al[i], bh[j], acc[i][j], 0, 0, 0);
            }

        __syncthreads();
    }

    // ---- epilogue ----
    const float s = scalePtr[scaleIdx];
    #pragma unroll
    for (int i = 0; i < 4; ++i) {
        #pragma unroll
        for (int j = 0; j < NJ; ++j) {
            const int gr0 = mBase + waveM + i * 16 + quad * 4;
            const int gc  = nBase + waveN + j * 16 + l16;
            #pragma unroll
            for (int r2 = 0; r2 < 4; ++r2) {
                size_t idx = (size_t)(gr0 + r2) * ldOut + gc;
                float a = acc[i][j][r2];
                if constexpr (EPI == 0) {
                    float v = s * a;
                    short h = f2b(v); Oh[idx] = h; Ol[idx] = f2b(v - b2f(h));
                } else if constexpr (EPI == 1) {
                    float v = a - Yaux[idx];
                    short h = f2b(v); Oh[idx] = h; Ol[idx] = f2b(v - b2f(h));
                } else {
                    float xv = b2f(Xh[idx]) + b2f(Xl[idx]);
                    outF[idx] = xv - s * a;
                }
            }
        }
    }
}

// cast A and W(=A^T) to bf16 hi/lo planes once per launch
__global__ void precast_kernel(const float* __restrict__ A,
                               short* __restrict__ Ahi, short* __restrict__ Alo,
                               const float* __restrict__ W,
                               short* __restrict__ WThi, short* __restrict__ WTlo, int n)
{
    int idx = blockIdx.x * 256 + threadIdx.x;
    int stride = gridDim.x * 256;
    for (int i = idx; i < n; i += stride) {
        float a = A[i];
        short h = f2b(a);
        Ahi[i] = h; Alo[i] = f2b(a - b2f(h));
        float w = W[i];
        short wh = f2b(w);
        WThi[i] = wh; WTlo[i] = f2b(w - b2f(wh));
    }
}

// one wave per row of z[.,2048]: exact kSel-th largest |z| (binary search on
// float bits), then hard-keep / soft-shrink; write x as bf16 hi/lo planes
// (+ fp32 in place on the final iteration).
__global__ __launch_bounds__(256) void shrink_kernel(
    float* __restrict__ z, short* __restrict__ Xhi, short* __restrict__ Xlo,
    const float* __restrict__ betaPtr, int tIdx, int kSel, int writeF32)
{
    const int tid  = threadIdx.x;
    const int wid  = tid >> 6;
    const int lane = tid & 63;
    const long long row = (long long)blockIdx.x * 4 + wid;
    const float beta = betaPtr[tIdx];
    float* zr = z + row * 2048;

    float v[32];
    #pragma unroll
    for (int c = 0; c < 8; ++c) {
        float4 f = ((const float4*)zr)[c * 64 + lane];
        v[c * 4 + 0] = f.x; v[c * 4 + 1] = f.y; v[c * 4 + 2] = f.z; v[c * 4 + 3] = f.w;
    }
    unsigned a[32];
    #pragma unroll
    for (int i = 0; i < 32; ++i) a[i] = __float_as_uint(fabsf(v[i]));

    unsigned lo = 0u, hi = 0x7F800000u;
    for (int it = 0; it < 31; ++it) {
        unsigned mid = (lo + hi) >> 1;
        int cnt = 0;
        #pragma unroll
        for (int i = 0; i < 32; ++i) cnt += (a[i] >= mid) ? 1 : 0;
        #pragma unroll
        for (int off = 32; off >= 1; off >>= 1) cnt += __shfl_xor(cnt, off, 64);
        if (cnt >= kSel) lo = mid; else hi = mid;
    }
    const unsigned thr = lo;

    #pragma unroll
    for (int i = 0; i < 32; ++i) {
        if (a[i] < thr) {
            float av   = __uint_as_float(a[i]);
            float soft = fmaxf(av - beta, 0.f);
            v[i] = copysignf(soft, v[i]);
        }
    }
    #pragma unroll
    for (int c = 0; c < 8; ++c) {
        size_t col = (size_t)(c * 64 + lane) * 4;
        short4v h, l;
        #pragma unroll
        for (int e = 0; e < 4; ++e) {
            float xv = v[c * 4 + e];
            short hh = f2b(xv);
            ((short*)&h)[e] = hh;
            ((short*)&l)[e] = f2b(xv - b2f(hh));
        }
        *(short4v*)(Xhi + row * 2048 + col) = h;
        *(short4v*)(Xlo + row * 2048 + col) = l;
        if (writeF32) {
            float4 f;
            f.x = v[c * 4 + 0]; f.y = v[c * 4 + 1]; f.z = v[c * 4 + 2]; f.w = v[c * 4 + 3];
            ((float4*)zr)[c * 64 + lane] = f;
        }
    }
}

extern "C" void kernel_launch(void* const* d_in, const int* in_sizes, int n_in,
                              void* d_out, int out_size, void* d_ws, size_t ws_size,
                              hipStream_t stream)
{
    const float* y    = (const float*)d_in[0];   // [8192,512]
    const float* A    = (const float*)d_in[1];   // [512,2048]
    const float* W    = (const float*)d_in[2];   // [2048,512] == A^T exactly
    const float* beta = (const float*)d_in[3];   // [6]
    const float* mu   = (const float*)d_in[4];   // [6]
    float* out = (float*)d_out;                  // z / final x (fp32)

    // workspace layout (~92 MB)
    short* Ahi  = (short*)d_ws;            // [512][2048]
    short* Alo  = Ahi  + 512 * 2048;
    short* AThi = Alo  + 512 * 2048;       // [2048][512]
    short* ATlo = AThi + 2048 * 512;
    short* xhi  = ATlo + 2048 * 512;       // [8192][2048]
    short* xlo  = xhi  + 8192 * 2048;
    short* rhi  = xlo  + 8192 * 2048;      // [8192][512]
    short* rlo  = rhi  + 8192 * 512;

    precast_kernel<<<1024, 256, 0, stream>>>(A, Ahi, Alo, W, AThi, ATlo, 512 * 2048);

    // x0 planes = split(mu0 * y @ A)   (Bop = A -> B^T layout = AT planes)
    gemm_kernel<4, 0, true><<<dim3(16, 64), 256, 0, stream>>>(
        y, nullptr, nullptr, 512, AThi, ATlo, 512,
        nullptr, nullptr, nullptr, nullptr, xhi, xlo, mu, 0, 512, 2048);

    for (int t = 1; t <= 5; ++t) {
        double p = 0.012 * t; if (p > 0.12) p = 0.12;
        int kSel = (int)(p * 2048.0);   // 24,49,73,98,122

        // r planes = split(x @ A^T - y)   (Bop = A^T -> B^T layout = A planes)
        gemm_kernel<2, 1, false><<<dim3(8, 64), 256, 0, stream>>>(
            nullptr, xhi, xlo, 2048, Ahi, Alo, 2048,
            y, nullptr, nullptr, nullptr, rhi, rlo, mu, t, 2048, 512);

        // z = x - mu_t * (r @ A)  -> d_out fp32
        gemm_kernel<4, 2, false><<<dim3(16, 64), 256, 0, stream>>>(
            nullptr, rhi, rlo, 512, AThi, ATlo, 512,
            nullptr, xhi, xlo, out, nullptr, nullptr, mu, t, 512, 2048);

        // x = shrink(z) -> planes (+ fp32 at t=5)
        shrink_kernel<<<2048, 256, 0, stream>>>(out, xhi, xlo, beta, t, kSel, t == 5 ? 1 : 0);
    }
}

// Round 6
// 1022.090 us; speedup vs baseline: 1.2493x; 1.1259x over previous
//
#include <hip/hip_runtime.h>
#include <hip/hip_bf16.h>

// ---------------------------------------------------------------------------
// TiLISTA: M=512, N=2048, B=8192, T=5
//   x0 = mu0 * y @ A
//   for t=1..5:
//     r = x @ A^T - y        [B,512]   (bf16 hi/lo planes in ws)
//     z = x - mu_t * (r @ A) [B,2048]  (fp32 in d_out)
//     x = shrink(z, beta_t, k_t)       (bf16 hi/lo planes in ws)
// All GEMM operands are pre-split bf16 hi/lo planes -> staging is a pure copy
// via global_load_lds (width 16). 3-term split MFMA (hi*hi+hi*lo+lo*hi) gives
// ~2^-17 effective input precision (z error ~1e-5 -> single top-k tie-flip
// floor, absmax 1.17e-2 — measured R3). shrink = exact k-th |z| binary search.
// R6: XCD flat-swizzle (m = flat%64) so all n-blocks of one m-row-block land
// on the same XCD -> x-planes fetched once per XCD (R3: FETCH 279MB, 3x ideal).
// ---------------------------------------------------------------------------

typedef __bf16 bf16x8 __attribute__((ext_vector_type(8)));
typedef float  f32x4  __attribute__((ext_vector_type(4)));
typedef short  short4v __attribute__((ext_vector_type(4)));

__device__ __forceinline__ short f2b(float f) {
    unsigned u = __float_as_uint(f);
    unsigned r = (u + 0x7FFFu + ((u >> 16) & 1u)) >> 16;
    return (short)(r & 0xFFFFu);
}
__device__ __forceinline__ float b2f(short h) {
    return __uint_as_float(((unsigned)(unsigned short)h) << 16);
}

__device__ __forceinline__ void gl_lds16(const short* g, short* lds) {
    __builtin_amdgcn_global_load_lds(
        (const __attribute__((address_space(1))) void*)g,
        (__attribute__((address_space(3))) void*)lds, 16, 0, 0);
}

// out[m][n] = epilogue( sum_k Aop[m][k] * Bop[k][n] )
// Aop: bf16 hi/lo planes [M][K] (or fp32 Af split on stage if AF32).
// Bop: bf16 hi/lo planes in B^T layout [n][k].
// EPI 0: split(s*acc) -> Oh/Ol planes            (h step)
// EPI 1: split(acc - Y) -> Oh/Ol planes          (r step; Y = y fp32)
// EPI 2: outF = (Xh+Xl) - s*acc  (fp32)          (z step; X = x planes)
// Grid (NX,64); flat id swizzle: m-block = flat%64, n-block = flat/64 -> all
// blocks sharing an m-row-block have flat == m (mod 8) -> same XCD L2.
template<int NJ, int EPI, bool AF32>
__global__ __launch_bounds__(256) void gemm_kernel(
    const float* __restrict__ Af,
    const short* __restrict__ Ah_p, const short* __restrict__ Al_p, int lda,
    const short* __restrict__ Bh_p, const short* __restrict__ Bl_p, int ldb,
    const float* __restrict__ Yaux,
    const short* __restrict__ Xh, const short* __restrict__ Xl,
    float* outF, short* Oh, short* Ol,
    const float* __restrict__ scalePtr, int scaleIdx, int K, int ldOut)
{
    constexpr int BN = 32 * NJ;   // 128 (NJ=4) or 64 (NJ=2)
    // packed SK=32 (64B rows) — required by global_load_lds lane-contiguity
    __shared__ short AsH[128 * 32];
    __shared__ short AsL[128 * 32];
    __shared__ short BsH[BN * 32];
    __shared__ short BsL[BN * 32];

    const int tid  = threadIdx.x;
    const int wid  = tid >> 6;
    const int lane = tid & 63;
    const int quad = lane >> 4;
    const int l16  = lane & 15;
    const int waveM = (wid >> 1) * 64;
    const int waveN = (wid & 1) * (16 * NJ);

    const int flat  = blockIdx.x + gridDim.x * blockIdx.y;
    const int mBase = (flat & 63) * 128;
    const int nBase = (flat >> 6) * BN;

    f32x4 acc[4][NJ] = {};

    for (int k0 = 0; k0 < K; k0 += 32) {
        // ---- stage A tile: 128 rows x 32 k ----
        if constexpr (AF32) {
            #pragma unroll
            for (int it = 0; it < 4; ++it) {
                int f4  = tid + it * 256;
                int row = f4 >> 3;
                int kq  = f4 & 7;
                const float4 v = *(const float4*)(Af + (size_t)(mBase + row) * lda + k0 + kq * 4);
                short4v h, l;
                h.x = f2b(v.x); l.x = f2b(v.x - b2f(h.x));
                h.y = f2b(v.y); l.y = f2b(v.y - b2f(h.y));
                h.z = f2b(v.z); l.z = f2b(v.z - b2f(h.z));
                h.w = f2b(v.w); l.w = f2b(v.w - b2f(h.w));
                *(short4v*)(&AsH[row * 32 + kq * 4]) = h;
                *(short4v*)(&AsL[row * 32 + kq * 4]) = l;
            }
        } else {
            #pragma unroll
            for (int rr = 0; rr < 2; ++rr) {
                int c   = rr * 256 + tid;       // 16B chunk id, 0..511
                int row = c >> 2;
                int ko  = (c & 3) * 8;
                size_t g = (size_t)(mBase + row) * lda + k0 + ko;
                gl_lds16(Ah_p + g, &AsH[(rr * 256 + wid * 64) * 8]);
                gl_lds16(Al_p + g, &AsL[(rr * 256 + wid * 64) * 8]);
            }
        }
        // ---- stage B tile: BN rows x 32 k ----
        #pragma unroll
        for (int rr = 0; rr < BN / 64; ++rr) {
            int c   = rr * 256 + tid;
            int row = c >> 2;
            int ko  = (c & 3) * 8;
            size_t g = (size_t)(nBase + row) * ldb + k0 + ko;
            gl_lds16(Bh_p + g, &BsH[(rr * 256 + wid * 64) * 8]);
            gl_lds16(Bl_p + g, &BsL[(rr * 256 + wid * 64) * 8]);
        }
        __syncthreads();   // drains vmcnt (global_load_lds) before LDS reads

        bf16x8 ah[4], al[4], bh[NJ], bl[NJ];
        #pragma unroll
        for (int i = 0; i < 4; ++i) {
            int off = (waveM + i * 16 + l16) * 32 + quad * 8;
            ah[i] = *(const bf16x8*)(&AsH[off]);
            al[i] = *(const bf16x8*)(&AsL[off]);
        }
        #pragma unroll
        for (int j = 0; j < NJ; ++j) {
            int off = (waveN + j * 16 + l16) * 32 + quad * 8;
            bh[j] = *(const bf16x8*)(&BsH[off]);
            bl[j] = *(const bf16x8*)(&BsL[off]);
        }
        #pragma unroll
        for (int i = 0; i < 4; ++i)
            #pragma unroll
            for (int j = 0; j < NJ; ++j) {
                acc[i][j] = __builtin_amdgcn_mfma_f32_16x16x32_bf16(ah[i], bh[j], acc[i][j], 0, 0, 0);
                acc[i][j] = __builtin_amdgcn_mfma_f32_16x16x32_bf16(ah[i], bl[j], acc[i][j], 0, 0, 0);
                acc[i][j] = __builtin_amdgcn_mfma_f32_16x16x32_bf16(al[i], bh[j], acc[i][j], 0, 0, 0);
            }

        __syncthreads();
    }

    // ---- epilogue ----
    const float s = scalePtr[scaleIdx];
    #pragma unroll
    for (int i = 0; i < 4; ++i) {
        #pragma unroll
        for (int j = 0; j < NJ; ++j) {
            const int gr0 = mBase + waveM + i * 16 + quad * 4;
            const int gc  = nBase + waveN + j * 16 + l16;
            #pragma unroll
            for (int r2 = 0; r2 < 4; ++r2) {
                size_t idx = (size_t)(gr0 + r2) * ldOut + gc;
                float a = acc[i][j][r2];
                if constexpr (EPI == 0) {
                    float v = s * a;
                    short h = f2b(v); Oh[idx] = h; Ol[idx] = f2b(v - b2f(h));
                } else if constexpr (EPI == 1) {
                    float v = a - Yaux[idx];
                    short h = f2b(v); Oh[idx] = h; Ol[idx] = f2b(v - b2f(h));
                } else {
                    float xv = b2f(Xh[idx]) + b2f(Xl[idx]);
                    outF[idx] = xv - s * a;
                }
            }
        }
    }
}

// cast A and W(=A^T) to bf16 hi/lo planes once per launch
__global__ void precast_kernel(const float* __restrict__ A,
                               short* __restrict__ Ahi, short* __restrict__ Alo,
                               const float* __restrict__ W,
                               short* __restrict__ WThi, short* __restrict__ WTlo, int n)
{
    int idx = blockIdx.x * 256 + threadIdx.x;
    int stride = gridDim.x * 256;
    for (int i = idx; i < n; i += stride) {
        float a = A[i];
        short h = f2b(a);
        Ahi[i] = h; Alo[i] = f2b(a - b2f(h));
        float w = W[i];
        short wh = f2b(w);
        WThi[i] = wh; WTlo[i] = f2b(w - b2f(wh));
    }
}

// one wave per row of z[.,2048]: exact kSel-th largest |z| (binary search on
// float bits), then hard-keep / soft-shrink; write x as bf16 hi/lo planes
// (+ fp32 in place on the final iteration).
__global__ __launch_bounds__(256) void shrink_kernel(
    float* __restrict__ z, short* __restrict__ Xhi, short* __restrict__ Xlo,
    const float* __restrict__ betaPtr, int tIdx, int kSel, int writeF32)
{
    const int tid  = threadIdx.x;
    const int wid  = tid >> 6;
    const int lane = tid & 63;
    const long long row = (long long)blockIdx.x * 4 + wid;
    const float beta = betaPtr[tIdx];
    float* zr = z + row * 2048;

    float v[32];
    #pragma unroll
    for (int c = 0; c < 8; ++c) {
        float4 f = ((const float4*)zr)[c * 64 + lane];
        v[c * 4 + 0] = f.x; v[c * 4 + 1] = f.y; v[c * 4 + 2] = f.z; v[c * 4 + 3] = f.w;
    }
    unsigned a[32];
    #pragma unroll
    for (int i = 0; i < 32; ++i) a[i] = __float_as_uint(fabsf(v[i]));

    unsigned lo = 0u, hi = 0x7F800000u;
    for (int it = 0; it < 31; ++it) {
        unsigned mid = (lo + hi) >> 1;
        int cnt = 0;
        #pragma unroll
        for (int i = 0; i < 32; ++i) cnt += (a[i] >= mid) ? 1 : 0;
        #pragma unroll
        for (int off = 32; off >= 1; off >>= 1) cnt += __shfl_xor(cnt, off, 64);
        if (cnt >= kSel) lo = mid; else hi = mid;
    }
    const unsigned thr = lo;

    #pragma unroll
    for (int i = 0; i < 32; ++i) {
        if (a[i] < thr) {
            float av   = __uint_as_float(a[i]);
            float soft = fmaxf(av - beta, 0.f);
            v[i] = copysignf(soft, v[i]);
        }
    }
    #pragma unroll
    for (int c = 0; c < 8; ++c) {
        size_t col = (size_t)(c * 64 + lane) * 4;
        short4v h, l;
        #pragma unroll
        for (int e = 0; e < 4; ++e) {
            float xv = v[c * 4 + e];
            short hh = f2b(xv);
            ((short*)&h)[e] = hh;
            ((short*)&l)[e] = f2b(xv - b2f(hh));
        }
        *(short4v*)(Xhi + row * 2048 + col) = h;
        *(short4v*)(Xlo + row * 2048 + col) = l;
        if (writeF32) {
            float4 f;
            f.x = v[c * 4 + 0]; f.y = v[c * 4 + 1]; f.z = v[c * 4 + 2]; f.w = v[c * 4 + 3];
            ((float4*)zr)[c * 64 + lane] = f;
        }
    }
}

extern "C" void kernel_launch(void* const* d_in, const int* in_sizes, int n_in,
                              void* d_out, int out_size, void* d_ws, size_t ws_size,
                              hipStream_t stream)
{
    const float* y    = (const float*)d_in[0];   // [8192,512]
    const float* A    = (const float*)d_in[1];   // [512,2048]
    const float* W    = (const float*)d_in[2];   // [2048,512] == A^T exactly
    const float* beta = (const float*)d_in[3];   // [6]
    const float* mu   = (const float*)d_in[4];   // [6]
    float* out = (float*)d_out;                  // z / final x (fp32)

    // workspace layout (~92 MB)
    short* Ahi  = (short*)d_ws;            // [512][2048]
    short* Alo  = Ahi  + 512 * 2048;
    short* AThi = Alo  + 512 * 2048;       // [2048][512]
    short* ATlo = AThi + 2048 * 512;
    short* xhi  = ATlo + 2048 * 512;       // [8192][2048]
    short* xlo  = xhi  + (size_t)8192 * 2048;
    short* rhi  = xlo  + (size_t)8192 * 2048;  // [8192][512]
    short* rlo  = rhi  + 8192 * 512;

    precast_kernel<<<1024, 256, 0, stream>>>(A, Ahi, Alo, W, AThi, ATlo, 512 * 2048);

    // x0 planes = split(mu0 * y @ A)   (Bop = A -> B^T layout = AT planes)
    gemm_kernel<4, 0, true><<<dim3(16, 64), 256, 0, stream>>>(
        y, nullptr, nullptr, 512, AThi, ATlo, 512,
        nullptr, nullptr, nullptr, nullptr, xhi, xlo, mu, 0, 512, 2048);

    for (int t = 1; t <= 5; ++t) {
        double p = 0.012 * t; if (p > 0.12) p = 0.12;
        int kSel = (int)(p * 2048.0);   // 24,49,73,98,122

        // r planes = split(x @ A^T - y)   (Bop = A^T -> B^T layout = A planes)
        gemm_kernel<2, 1, false><<<dim3(8, 64), 256, 0, stream>>>(
            nullptr, xhi, xlo, 2048, Ahi, Alo, 2048,
            y, nullptr, nullptr, nullptr, rhi, rlo, mu, t, 2048, 512);

        // z = x - mu_t * (r @ A)  -> d_out fp32
        gemm_kernel<4, 2, false><<<dim3(16, 64), 256, 0, stream>>>(
            nullptr, rhi, rlo, 512, AThi, ATlo, 512,
            nullptr, xhi, xlo, out, nullptr, nullptr, mu, t, 512, 2048);

        // x = shrink(z) -> planes (+ fp32 in d_out at t=5)
        shrink_kernel<<<2048, 256, 0, stream>>>(out, xhi, xlo, beta, t, kSel, t == 5 ? 1 : 0);
    }
}

// Round 8
// 978.539 us; speedup vs baseline: 1.3049x; 1.0445x over previous
//
#include <hip/hip_runtime.h>

// ---------------------------------------------------------------------------
// TiLISTA: M=512, N=2048, B=8192, T=5 — i8 dual-plane GEMMs, fp32 x state.
//   x0 = mu0 * y @ A                      (fp32 in d_out)
//   for t=1..5:
//     r = x @ A^T - y        (fp32 in ws -> per-row i8 planes)
//     z = x - mu_t * (r @ A) (x read fp32 from d_out, z written in place)
//     x = shrink(z,beta,k)   (fp32 in d_out + i8 planes for next GEMM)
// GEMM operands: per-row q = q1*128 + q0 (|q|<=16256, ~15 bits of rowmax).
// 3 x mfma_i32_16x16x64_i8 per 64-K: a1b1->accH, a1b0+a0b1->accM;
// v = sA*sB*(accH*16384 + accM*128). Numerics: GEMM-input quant noise
// averages through A's unit-norm columns (~6e-6); x kept fp32 so direct
// storage error is 0. z error ~1e-5 = single tie-flip floor (R3-measured).
// R8 FIX: B-staging loop count was BN/128 = 0 for NJ=2 -> B tile never
// staged (absmax 29!). Correct count = BN*64/(16*256) = BN/64.
// Grid flat-swizzle: m-block = flat%64 -> same-m blocks share an XCD L2 (R6).
// shrink = exact k-th-largest |z| via binary search on float bits, 1 wave/row.
// ---------------------------------------------------------------------------

typedef int int4v __attribute__((ext_vector_type(4)));

__device__ __forceinline__ void quant2(float v, float inv_s,
                                       signed char& q1, signed char& q0) {
    int q = __float2int_rn(v * inv_s);
    q = q > 16256 ? 16256 : (q < -16256 ? -16256 : q);
    int hi = (q + 64) >> 7;            // round-half-up -> [-127,127]
    q1 = (signed char)hi;
    q0 = (signed char)(q - (hi << 7)); // [-64,63]
}

__device__ __forceinline__ void gl_lds16(const signed char* g, signed char* lds) {
    __builtin_amdgcn_global_load_lds(
        (const __attribute__((address_space(1))) void*)g,
        (__attribute__((address_space(3))) void*)lds, 16, 0, 0);
}

// out[m][n] = epilogue( sum_k Aop[m][k]*Bop[k][n] ); Bop in B^T layout [n][k].
// EPI 0: outF = mu * v                  (x0; A=y planes, B=AT planes)
// EPI 1: outF = v - yF                  (r;  A=x planes, B=A planes)
// EPI 2: outF = Yaux - mu * v, in place (z;  A=r planes, B=AT planes, Yaux=x)
template<int NJ, int EPI>
__global__ __launch_bounds__(256) void gemm_i8(
    const signed char* __restrict__ A1, const signed char* __restrict__ A0, int lda,
    const signed char* __restrict__ B1, const signed char* __restrict__ B0, int ldb,
    const float* __restrict__ sAv,   // per-row scale of A-operand
    const float* __restrict__ sBv,   // per-row scale of B-operand (per out col)
    const float* __restrict__ Yaux,  // EPI1: y fp32 ; EPI2: x fp32 (= outF)
    float* __restrict__ outF,
    const float* __restrict__ muPtr, int muIdx, int K, int ldOut)
{
    constexpr int BN = 32 * NJ;      // 128 (NJ=4) or 64 (NJ=2)
    __shared__ signed char As1[128 * 64];
    __shared__ signed char As0[128 * 64];
    __shared__ signed char Bs1[BN * 64];
    __shared__ signed char Bs0[BN * 64];

    const int tid  = threadIdx.x;
    const int wid  = tid >> 6;
    const int lane = tid & 63;
    const int quad = lane >> 4;
    const int l16  = lane & 15;
    const int waveM = (wid >> 1) * 64;
    const int waveN = (wid & 1) * (16 * NJ);

    const int flat  = blockIdx.x + gridDim.x * blockIdx.y;
    const int mBase = (flat & 63) * 128;
    const int nBase = (flat >> 6) * BN;

    int4v accH[4][NJ] = {};
    int4v accM[4][NJ] = {};

    for (int k0 = 0; k0 < K; k0 += 64) {
        // ---- stage A tile: 128 rows x 64 k (two i8 planes) ----
        #pragma unroll
        for (int rr = 0; rr < 2; ++rr) {
            int c   = rr * 256 + tid;          // 16B chunk id, 0..511
            int row = c >> 2;
            int ko  = (c & 3) * 16;
            size_t ga = (size_t)(mBase + row) * lda + k0 + ko;
            size_t doff = (size_t)((rr * 256 + wid * 64) * 16);
            gl_lds16(A1 + ga, As1 + doff);
            gl_lds16(A0 + ga, As0 + doff);
        }
        // ---- stage B tile: BN rows x 64 k ----
        // chunk count = BN*64B / 16B = BN*4; iterations = BN*4/256 = BN/64
        #pragma unroll
        for (int rr = 0; rr < BN / 64; ++rr) {
            int c   = rr * 256 + tid;
            int row = c >> 2;
            int ko  = (c & 3) * 16;
            size_t gb = (size_t)(nBase + row) * ldb + k0 + ko;
            size_t doff = (size_t)((rr * 256 + wid * 64) * 16);
            gl_lds16(B1 + gb, Bs1 + doff);
            gl_lds16(B0 + gb, Bs0 + doff);
        }
        __syncthreads();   // drains vmcnt before LDS reads

        int4v a1[4], a0[4], b1[NJ], b0[NJ];
        #pragma unroll
        for (int i = 0; i < 4; ++i) {
            int off = (waveM + i * 16 + l16) * 64 + quad * 16;
            a1[i] = *(const int4v*)(&As1[off]);
            a0[i] = *(const int4v*)(&As0[off]);
        }
        #pragma unroll
        for (int j = 0; j < NJ; ++j) {
            int off = (waveN + j * 16 + l16) * 64 + quad * 16;
            b1[j] = *(const int4v*)(&Bs1[off]);
            b0[j] = *(const int4v*)(&Bs0[off]);
        }
        #pragma unroll
        for (int i = 0; i < 4; ++i)
            #pragma unroll
            for (int j = 0; j < NJ; ++j) {
                accH[i][j] = __builtin_amdgcn_mfma_i32_16x16x64_i8(a1[i], b1[j], accH[i][j], 0, 0, 0);
                accM[i][j] = __builtin_amdgcn_mfma_i32_16x16x64_i8(a1[i], b0[j], accM[i][j], 0, 0, 0);
                accM[i][j] = __builtin_amdgcn_mfma_i32_16x16x64_i8(a0[i], b1[j], accM[i][j], 0, 0, 0);
            }

        __syncthreads();
    }

    const float mu = muPtr[muIdx];
    #pragma unroll
    for (int i = 0; i < 4; ++i) {
        #pragma unroll
        for (int j = 0; j < NJ; ++j) {
            const int gr0 = mBase + waveM + i * 16 + quad * 4;
            const int gc  = nBase + waveN + j * 16 + l16;
            const float sB = sBv[gc];
            #pragma unroll
            for (int r2 = 0; r2 < 4; ++r2) {
                const int    gr  = gr0 + r2;
                const size_t idx = (size_t)gr * ldOut + gc;
                const float  sA  = sAv[gr];
                float v = sA * sB * ((float)accH[i][j][r2] * 16384.f
                                   + (float)accM[i][j][r2] * 128.f);
                if constexpr (EPI == 0)      outF[idx] = mu * v;
                else if constexpr (EPI == 1) outF[idx] = v - Yaux[idx];
                else                         outF[idx] = Yaux[idx] - mu * v;
            }
        }
    }
}

// per-row quantization of a fp32 matrix to i8 dual planes + row scale
template<int COLS>
__global__ __launch_bounds__(256) void rowquant_kernel(
    const float* __restrict__ src,
    signed char* __restrict__ q1, signed char* __restrict__ q0,
    float* __restrict__ scale)
{
    const int wid  = threadIdx.x >> 6;
    const int lane = threadIdx.x & 63;
    const long long row = (long long)blockIdx.x * 4 + wid;
    constexpr int EP = COLS / 256;   // float4 per lane
    const float* s = src + row * COLS;

    float v[EP * 4];
    #pragma unroll
    for (int c = 0; c < EP; ++c) {
        float4 f = ((const float4*)s)[c * 64 + lane];
        v[c * 4 + 0] = f.x; v[c * 4 + 1] = f.y; v[c * 4 + 2] = f.z; v[c * 4 + 3] = f.w;
    }
    float mx = 0.f;
    #pragma unroll
    for (int i = 0; i < EP * 4; ++i) mx = fmaxf(mx, fabsf(v[i]));
    #pragma unroll
    for (int off = 32; off >= 1; off >>= 1) mx = fmaxf(mx, __shfl_xor(mx, off, 64));
    mx = fmaxf(mx, 1e-20f);
    if (lane == 0) scale[row] = mx / 16256.f;
    const float inv = 16256.f / mx;

    #pragma unroll
    for (int c = 0; c < EP; ++c) {
        size_t col = (size_t)(c * 64 + lane) * 4;
        signed char h[4], l[4];
        #pragma unroll
        for (int e = 0; e < 4; ++e) quant2(v[c * 4 + e], inv, h[e], l[e]);
        *(char4*)(q1 + row * COLS + col) = *(char4*)h;
        *(char4*)(q0 + row * COLS + col) = *(char4*)l;
    }
}

// one wave per row of z[.,2048]: optional exact k-th-largest |z| hard/soft
// threshold, per-row quantize x -> i8 planes + scale, optionally write x fp32.
__global__ __launch_bounds__(256) void shrink_kernel(
    float* __restrict__ z,
    signed char* __restrict__ X1, signed char* __restrict__ X0,
    float* __restrict__ sX,
    const float* __restrict__ betaPtr, int tIdx, int kSel, int writeF32)
{
    const int wid  = threadIdx.x >> 6;
    const int lane = threadIdx.x & 63;
    const long long row = (long long)blockIdx.x * 4 + wid;
    float* zr = z + row * 2048;

    float v[32];
    #pragma unroll
    for (int c = 0; c < 8; ++c) {
        float4 f = ((const float4*)zr)[c * 64 + lane];
        v[c * 4 + 0] = f.x; v[c * 4 + 1] = f.y; v[c * 4 + 2] = f.z; v[c * 4 + 3] = f.w;
    }

    if (kSel > 0) {
        const float beta = betaPtr[tIdx];
        unsigned a[32];
        #pragma unroll
        for (int i = 0; i < 32; ++i) a[i] = __float_as_uint(fabsf(v[i]));

        unsigned lo = 0u, hi = 0x7F800000u;
        for (int it = 0; it < 31; ++it) {
            unsigned mid = (lo + hi) >> 1;
            int cnt = 0;
            #pragma unroll
            for (int i = 0; i < 32; ++i) cnt += (a[i] >= mid) ? 1 : 0;
            #pragma unroll
            for (int off = 32; off >= 1; off >>= 1) cnt += __shfl_xor(cnt, off, 64);
            if (cnt >= kSel) lo = mid; else hi = mid;
        }
        const unsigned thr = lo;
        #pragma unroll
        for (int i = 0; i < 32; ++i) {
            if (a[i] < thr) {
                float av   = __uint_as_float(a[i]);
                float soft = fmaxf(av - beta, 0.f);
                v[i] = copysignf(soft, v[i]);
            }
        }
    }

    float mx = 0.f;
    #pragma unroll
    for (int i = 0; i < 32; ++i) mx = fmaxf(mx, fabsf(v[i]));
    #pragma unroll
    for (int off = 32; off >= 1; off >>= 1) mx = fmaxf(mx, __shfl_xor(mx, off, 64));
    mx = fmaxf(mx, 1e-20f);
    if (lane == 0) sX[row] = mx / 16256.f;
    const float inv = 16256.f / mx;

    #pragma unroll
    for (int c = 0; c < 8; ++c) {
        size_t col = (size_t)(c * 64 + lane) * 4;
        signed char h[4], l[4];
        #pragma unroll
        for (int e = 0; e < 4; ++e) quant2(v[c * 4 + e], inv, h[e], l[e]);
        *(char4*)(X1 + row * 2048 + col) = *(char4*)h;
        *(char4*)(X0 + row * 2048 + col) = *(char4*)l;
        if (writeF32) {
            float4 f;
            f.x = v[c * 4 + 0]; f.y = v[c * 4 + 1]; f.z = v[c * 4 + 2]; f.w = v[c * 4 + 3];
            ((float4*)zr)[c * 64 + lane] = f;
        }
    }
}

extern "C" void kernel_launch(void* const* d_in, const int* in_sizes, int n_in,
                              void* d_out, int out_size, void* d_ws, size_t ws_size,
                              hipStream_t stream)
{
    const float* y    = (const float*)d_in[0];   // [8192,512]
    const float* A    = (const float*)d_in[1];   // [512,2048]
    const float* W    = (const float*)d_in[2];   // [2048,512] == A^T
    const float* beta = (const float*)d_in[3];   // [6]
    const float* mu   = (const float*)d_in[4];   // [6]
    float* out = (float*)d_out;                  // x / z fp32, in place

    // workspace (~68 MB)
    signed char* A1q  = (signed char*)d_ws;          // [512][2048]
    signed char* A0q  = A1q  + 512 * 2048;
    signed char* AT1q = A0q  + 512 * 2048;           // [2048][512]
    signed char* AT0q = AT1q + 2048 * 512;
    signed char* y1q  = AT0q + 2048 * 512;           // [8192][512]
    signed char* y0q  = y1q  + 8192 * 512;
    signed char* x1q  = y0q  + 8192 * 512;           // [8192][2048]
    signed char* x0q  = x1q  + (size_t)8192 * 2048;
    signed char* r1q  = x0q  + (size_t)8192 * 2048;  // [8192][512]
    signed char* r0q  = r1q  + 8192 * 512;
    float* rF  = (float*)(r0q + 8192 * 512);         // [8192][512] fp32
    float* sa  = rF + (size_t)8192 * 512;            // [512]
    float* sat = sa  + 512;                          // [2048]
    float* sy  = sat + 2048;                         // [8192]
    float* sx  = sy  + 8192;                         // [8192]
    float* sr  = sx  + 8192;                         // [8192]

    rowquant_kernel<2048><<<128, 256, 0, stream>>>(A, A1q, A0q, sa);
    rowquant_kernel<512><<<512, 256, 0, stream>>>(W, AT1q, AT0q, sat);
    rowquant_kernel<512><<<2048, 256, 0, stream>>>(y, y1q, y0q, sy);

    // x0 = mu0 * y @ A  -> d_out fp32   (A-op = y planes, B-op = AT planes)
    gemm_i8<4, 0><<<dim3(16, 64), 256, 0, stream>>>(
        y1q, y0q, 512, AT1q, AT0q, 512, sy, sat,
        nullptr, out, mu, 0, 512, 2048);
    // quantize x0 for GEMM use (kSel=0: values unchanged, no fp32 rewrite)
    shrink_kernel<<<2048, 256, 0, stream>>>(out, x1q, x0q, sx, beta, 0, 0, 0);

    for (int t = 1; t <= 5; ++t) {
        double p = 0.012 * t; if (p > 0.12) p = 0.12;
        int kSel = (int)(p * 2048.0);   // 24,49,73,98,122

        // r = x @ A^T - y  -> rF fp32   (A-op = x planes, B-op = A planes)
        gemm_i8<2, 1><<<dim3(8, 64), 256, 0, stream>>>(
            x1q, x0q, 2048, A1q, A0q, 2048, sx, sa,
            y, rF, mu, t, 2048, 512);
        // quantize r per-row
        rowquant_kernel<512><<<2048, 256, 0, stream>>>(rF, r1q, r0q, sr);

        // z = x - mu_t * (r @ A)  in place over d_out (x read fp32)
        gemm_i8<4, 2><<<dim3(16, 64), 256, 0, stream>>>(
            r1q, r0q, 512, AT1q, AT0q, 512, sr, sat,
            out, out, mu, t, 512, 2048);

        // x = shrink(z): fp32 in d_out + i8 planes for next iteration
        shrink_kernel<<<2048, 256, 0, stream>>>(out, x1q, x0q, sx, beta, t, kSel, 1);
    }
}